// Round 8
// baseline (684.527 us; speedup 1.0000x reference)
//
#include <hip/hip_runtime.h>
#include <hip/hip_bf16.h>

typedef __bf16 bf8 __attribute__((ext_vector_type(8)));
typedef float f4 __attribute__((ext_vector_type(4)));
typedef unsigned short u16;
typedef unsigned int u32;

#define B_ 4
#define P_ 2048
#define D_ 768
#define H_ 12
#define HD_ 64
// scale * log2(e): exp(s*0.125) = exp2(s * 0.18033688)
#define EXPC_ 0.18033688011112042f

typedef const __attribute__((address_space(1))) void gvoid;
typedef __attribute__((address_space(3))) void lvoid;

__device__ __forceinline__ void gl_lds16(const u16* g, u16* l) {
  __builtin_amdgcn_global_load_lds((gvoid*)g, (lvoid*)l, 16, 0, 0);
}

__device__ __forceinline__ u16 f2bf(float f) {  // RNE
  union { float f; u32 u; } c; c.f = f;
  u32 u = c.u;
  u += 0x7fffu + ((u >> 16) & 1u);
  return (u16)(u >> 16);
}

__device__ __forceinline__ float bf2f(u16 v) {
  union { u32 u; float f; } c; c.u = (u32)v << 16; return c.f;
}

__device__ __forceinline__ uint2 pack4(f4 v) {  // truncating 4xf32 -> 4xbf16
  union { float f; u32 u; } a, b, c, d;
  a.f = v[0]; b.f = v[1]; c.f = v[2]; d.f = v[3];
  uint2 r;
  r.x = (a.u >> 16) | (b.u & 0xffff0000u);
  r.y = (c.u >> 16) | (d.u & 0xffff0000u);
  return r;
}

__device__ __forceinline__ f4 unpack4(ushort4 v) {
  f4 r;
  r[0] = bf2f(v.x); r[1] = bf2f(v.y); r[2] = bf2f(v.z); r[3] = bf2f(v.w);
  return r;
}

__device__ __forceinline__ f4 unp2(u32 lo, u32 hi) {
  f4 r;
  r[0] = bf2f((u16)(lo & 0xffffu)); r[1] = bf2f((u16)(lo >> 16));
  r[2] = bf2f((u16)(hi & 0xffffu)); r[3] = bf2f((u16)(hi >> 16));
  return r;
}

__device__ __forceinline__ bf8 mkbf8(f4 a, f4 b) {
  union { uint4 u; bf8 v; } c;
  uint2 l = pack4(a), h = pack4(b);
  c.u = make_uint4(l.x, l.y, h.x, h.y);
  return c.v;
}

__device__ __forceinline__ f4 mfma16(bf8 a, bf8 b, f4 c) {
  return __builtin_amdgcn_mfma_f32_16x16x32_bf16(a, b, c, 0, 0, 0);
}

// fast exact-enough GELU (tanh form, exp2-based; max err ~1e-3 vs erf form)
__device__ __forceinline__ float gelu_f(float x) {
  float x2 = x * x;
  float y = x * (0.7978845608f + 0.0356774081f * x2);
  float t = __builtin_amdgcn_exp2f(y * 2.8853900818f);  // exp(2y)
  float r = __builtin_amdgcn_rcpf(t + 1.0f);
  return x - x * r;  // x * 0.5*(1+tanh(y))
}

#define ZERO44(acc)                    \
  {                                    \
    f4 z_ = {0.f, 0.f, 0.f, 0.f};      \
    for (int i_ = 0; i_ < 4; ++i_)     \
      for (int j_ = 0; j_ < 4; ++j_)   \
        acc[i_][j_] = z_;              \
  }

// ---------------- transpose-cast fp32 (R,C) -> bf16 (C,R) ----------------
__global__ __launch_bounds__(256) void tcast_k(const float* __restrict__ src,
                                               u16* __restrict__ dst, int R, int C) {
  __shared__ float t[32][33];
  int c0 = blockIdx.x * 32, r0 = blockIdx.y * 32;
  int tx = threadIdx.x & 31, ty = threadIdx.x >> 5;
  #pragma unroll
  for (int i = 0; i < 32; i += 8) {
    int r = r0 + ty + i, c = c0 + tx;
    t[ty + i][tx] = (r < R && c < C) ? src[(size_t)r * C + c] : 0.f;
  }
  __syncthreads();
  #pragma unroll
  for (int i = 0; i < 32; i += 8) {
    int c = c0 + ty + i, r = r0 + tx;
    if (c < C && r < R) dst[(size_t)c * R + r] = f2bf(t[tx][ty + i]);
  }
}

// ---------------- layernorm fp32 -> bf16 (LN1) ----------------
__global__ __launch_bounds__(256) void ln_k(const float* __restrict__ x,
                                            const float* __restrict__ g,
                                            const float* __restrict__ b,
                                            u16* __restrict__ out) {
  int row = blockIdx.x;
  const float* xr = x + (size_t)row * D_;
  float v0 = xr[threadIdx.x], v1 = xr[threadIdx.x + 256], v2 = xr[threadIdx.x + 512];
  float s = v0 + v1 + v2;
  float s2 = v0 * v0 + v1 * v1 + v2 * v2;
  #pragma unroll
  for (int o = 32; o > 0; o >>= 1) {
    s += __shfl_down(s, o, 64);
    s2 += __shfl_down(s2, o, 64);
  }
  __shared__ float a[4], a2[4];
  int wv = threadIdx.x >> 6;
  if ((threadIdx.x & 63) == 0) { a[wv] = s; a2[wv] = s2; }
  __syncthreads();
  s = a[0] + a[1] + a[2] + a[3];
  s2 = a2[0] + a2[1] + a2[2] + a2[3];
  float mean = s * (1.f / 768.f);
  float var = s2 * (1.f / 768.f) - mean * mean;
  float rstd = rsqrtf(var + 1e-5f);
  u16* orow = out + (size_t)row * D_;
  float vv[3] = {v0, v1, v2};
  #pragma unroll
  for (int j = 0; j < 3; ++j) {
    int i = threadIdx.x + j * 256;
    orow[i] = f2bf((vv[j] - mean) * rstd * g[i] + b[i]);
  }
}

// ---------------- x2 = x + O0 + O1; hln = LN(x2) ----------------
__global__ __launch_bounds__(256) void ln2add_k(const float* __restrict__ x,
                                                const u16* __restrict__ O0,
                                                const u16* __restrict__ O1,
                                                const float* __restrict__ g,
                                                const float* __restrict__ b,
                                                float* __restrict__ x2,
                                                u16* __restrict__ out) {
  int row = blockIdx.x;
  const float* xr = x + (size_t)row * D_;
  const u16* o0 = O0 + (size_t)row * D_;
  const u16* o1 = O1 + (size_t)row * D_;
  float vv[3];
  #pragma unroll
  for (int j = 0; j < 3; ++j) {
    int i = threadIdx.x + j * 256;
    vv[j] = xr[i] + bf2f(o0[i]) + bf2f(o1[i]);
  }
  float s = vv[0] + vv[1] + vv[2];
  float s2 = vv[0] * vv[0] + vv[1] * vv[1] + vv[2] * vv[2];
  #pragma unroll
  for (int o = 32; o > 0; o >>= 1) {
    s += __shfl_down(s, o, 64);
    s2 += __shfl_down(s2, o, 64);
  }
  __shared__ float a[4], a2[4];
  int wv = threadIdx.x >> 6;
  if ((threadIdx.x & 63) == 0) { a[wv] = s; a2[wv] = s2; }
  __syncthreads();
  s = a[0] + a[1] + a[2] + a[3];
  s2 = a2[0] + a2[1] + a2[2] + a2[3];
  float mean = s * (1.f / 768.f);
  float var = s2 * (1.f / 768.f) - mean * mean;
  float rstd = rsqrtf(var + 1e-5f);
  float* x2r = x2 + (size_t)row * D_;
  u16* orow = out + (size_t)row * D_;
  #pragma unroll
  for (int j = 0; j < 3; ++j) {
    int i = threadIdx.x + j * 256;
    x2r[i] = vv[j];
    orow[i] = f2bf((vv[j] - mean) * rstd * g[i] + b[i]);
  }
}

// ============ staged 128x128 GEMM core (m97 pattern), K-stride 32 ============
template <int K>
__device__ __forceinline__ void staged_core(const u16* __restrict__ Ab,
                                            const u16* __restrict__ Bb,
                                            u16* As, u16* Bs, f4 acc[4][4]) {
  const int wave = threadIdx.x >> 6, lane = threadIdx.x & 63;
  const int l15 = lane & 15, quad = lane >> 4;
  const int lrow = lane >> 2;
  const int lcol = (lane & 3) * 8;
  const int mw = (wave & 1) * 64, nw = (wave >> 1) * 64;
  for (int k0 = 0; k0 < K; k0 += 32) {
    const u16* ga = Ab + (size_t)(wave * 32 + lrow) * K + k0 + lcol;
    gl_lds16(ga, &As[(wave * 32) * 32]);
    gl_lds16(ga + (size_t)16 * K, &As[(wave * 32 + 16) * 32]);
    const u16* gb = Bb + (size_t)(wave * 32 + lrow) * K + k0 + lcol;
    gl_lds16(gb, &Bs[(wave * 32) * 32]);
    gl_lds16(gb + (size_t)16 * K, &Bs[(wave * 32 + 16) * 32]);
    __syncthreads();
    bf8 a[4], b[4];
    #pragma unroll
    for (int mt = 0; mt < 4; ++mt)
      a[mt] = *reinterpret_cast<const bf8*>(&As[(mw + mt * 16 + l15) * 32 + quad * 8]);
    #pragma unroll
    for (int nt = 0; nt < 4; ++nt)
      b[nt] = *reinterpret_cast<const bf8*>(&Bs[(nw + nt * 16 + l15) * 32 + quad * 8]);
    #pragma unroll
    for (int mt = 0; mt < 4; ++mt)
      #pragma unroll
      for (int nt = 0; nt < 4; ++nt)
        acc[mt][nt] = mfma16(a[mt], b[nt], acc[mt][nt]);
    __syncthreads();
  }
}

// ---------------- QKV GEMM staged; block-uniform Q/K/V section ----------------
__global__ __launch_bounds__(256) void gemm_qkv_k(const u16* __restrict__ hln,
                                                  const u16* __restrict__ wT,
                                                  const float* __restrict__ bias,
                                                  u16* __restrict__ Q, u16* __restrict__ Km,
                                                  u16* __restrict__ Vt) {
  __shared__ u16 As[128 * 32], Bs[128 * 32];
  int m0 = blockIdx.y * 128, n0 = blockIdx.x * 128;
  f4 acc[4][4];
  ZERO44(acc);
  staged_core<768>(hln + (size_t)m0 * 768, wT + (size_t)n0 * 768, As, Bs, acc);
  int wave = threadIdx.x >> 6, lane = threadIdx.x & 63, l15 = lane & 15, quad = lane >> 4;
  int mW = m0 + (wave & 1) * 64, nW = n0 + (wave >> 1) * 64;
  int which = blockIdx.x / 6;              // block-uniform: 0=Q 1=K 2=V
  int nloc0 = n0 - which * 768;            // local n base within section
  u16* dstQK = (which == 0) ? Q : Km;
  #pragma unroll
  for (int mt = 0; mt < 4; ++mt)
    #pragma unroll
    for (int nt = 0; nt < 4; ++nt)
      #pragma unroll
      for (int r = 0; r < 4; ++r) {
        int m = mW + mt * 16 + quad * 4 + r;
        int n = nW + nt * 16 + l15;
        float v = acc[mt][nt][r] + bias[n];
        u16 bv = f2bf(v);
        int b = m >> 11, p = m & 2047;
        int nn = nloc0 + (nW - n0) + nt * 16 + l15;
        int h = nn >> 6, d = nn & 63;
        if (which < 2)
          dstQK[((size_t)(b * H_ + h) * P_ + p) * HD_ + d] = bv;
        else
          Vt[((size_t)(b * H_ + h) * HD_ + d) * P_ + p] = bv;
      }
}

// ---------------- FC1 GEMM staged + fast GELU ----------------
__global__ __launch_bounds__(256) void gemm_fc1_k(const u16* __restrict__ A,
                                                  const u16* __restrict__ wT,
                                                  const float* __restrict__ bias,
                                                  u16* __restrict__ out) {
  __shared__ u16 As[128 * 32], Bs[128 * 32];
  int m0 = blockIdx.y * 128, n0 = blockIdx.x * 128;
  f4 acc[4][4];
  ZERO44(acc);
  staged_core<768>(A + (size_t)m0 * 768, wT + (size_t)n0 * 768, As, Bs, acc);
  int wave = threadIdx.x >> 6, lane = threadIdx.x & 63, l15 = lane & 15, quad = lane >> 4;
  int mW = m0 + (wave & 1) * 64, nW = n0 + (wave >> 1) * 64;
  #pragma unroll
  for (int mt = 0; mt < 4; ++mt)
    #pragma unroll
    for (int nt = 0; nt < 4; ++nt)
      #pragma unroll
      for (int r = 0; r < 4; ++r) {
        int m = mW + mt * 16 + quad * 4 + r;
        int n = nW + nt * 16 + l15;
        float v = gelu_f(acc[mt][nt][r] + bias[n]);
        out[(size_t)m * 3072 + n] = f2bf(v);
      }
}

// ---------------- FC2 GEMM staged (BM=128, BN=64), +bias +residual -> fp32 ----------------
__global__ __launch_bounds__(256) void gemm_fc2_k(const u16* __restrict__ A,
                                                  const u16* __restrict__ wT,
                                                  const float* __restrict__ bias,
                                                  const float* __restrict__ resid,
                                                  float* __restrict__ out) {
  __shared__ u16 As[128 * 32], Bs[64 * 32];
  int wave = threadIdx.x >> 6, lane = threadIdx.x & 63, l15 = lane & 15, quad = lane >> 4;
  int lrow = lane >> 2, lcol = (lane & 3) * 8;
  int m0 = blockIdx.y * 128, n0 = blockIdx.x * 64;
  const u16* Ab = A + (size_t)m0 * 3072;
  const u16* Bb = wT + (size_t)n0 * 3072;
  int mw = (wave & 1) * 64, nw = (wave >> 1) * 32;
  f4 acc[4][2];
  #pragma unroll
  for (int i = 0; i < 4; ++i)
    #pragma unroll
    for (int j = 0; j < 2; ++j) acc[i][j] = f4{0.f, 0.f, 0.f, 0.f};
  for (int k0 = 0; k0 < 3072; k0 += 32) {
    const u16* ga = Ab + (size_t)(wave * 32 + lrow) * 3072 + k0 + lcol;
    gl_lds16(ga, &As[(wave * 32) * 32]);
    gl_lds16(ga + (size_t)16 * 3072, &As[(wave * 32 + 16) * 32]);
    const u16* gb = Bb + (size_t)(wave * 16 + lrow) * 3072 + k0 + lcol;
    gl_lds16(gb, &Bs[(wave * 16) * 32]);
    __syncthreads();
    bf8 a[4], b[2];
    #pragma unroll
    for (int mt = 0; mt < 4; ++mt)
      a[mt] = *reinterpret_cast<const bf8*>(&As[(mw + mt * 16 + l15) * 32 + quad * 8]);
    #pragma unroll
    for (int nt = 0; nt < 2; ++nt)
      b[nt] = *reinterpret_cast<const bf8*>(&Bs[(nw + nt * 16 + l15) * 32 + quad * 8]);
    #pragma unroll
    for (int mt = 0; mt < 4; ++mt)
      #pragma unroll
      for (int nt = 0; nt < 2; ++nt)
        acc[mt][nt] = mfma16(a[mt], b[nt], acc[mt][nt]);
    __syncthreads();
  }
  int mW = m0 + mw, nW = n0 + nw;
  #pragma unroll
  for (int mt = 0; mt < 4; ++mt)
    #pragma unroll
    for (int nt = 0; nt < 2; ++nt)
      #pragma unroll
      for (int r = 0; r < 4; ++r) {
        int m = mW + mt * 16 + quad * 4 + r;
        int n = nW + nt * 16 + l15;
        size_t idx = (size_t)m * 768 + n;
        out[idx] = acc[mt][nt][r] + bias[n] + resid[idx];
      }
}

// ======== fused attention v4: 256-thread blocks, 4 waves x 3 heads each ========
// Grid 1024: g=id&7 -> (b,qs) per XCD (K/V L2-resident); pt=id>>3 (16 p-rows).
// Per 32-q tile: wave w computes S^T+exp for heads 3w..3w+2 -> E (odd-dword strides),
// 128 threads compute R=1/sum_h E, each wave rescales own E in regs for AV MFMA.
// 2 barriers/tile; multiple independent blocks per CU overlap barrier stalls.
__global__ __launch_bounds__(256) void attn_fused_k(const u16* __restrict__ Q,
                                                    const u16* __restrict__ Km,
                                                    const u16* __restrict__ Vt,
                                                    u16* __restrict__ O0,
                                                    u16* __restrict__ O1) {
  int id = blockIdx.x;
  int g = id & 7, pt = id >> 3;
  int b = g >> 1, qs = g & 1;
  int w = threadIdx.x >> 6, lane = threadIdx.x & 63, l15 = lane & 15, quad = lane >> 4;

  __shared__ __align__(16) char smem[27648];
  u32* E32 = reinterpret_cast<u32*>(smem);              // E[12][16] rows of 19 dwords (38 u16)
  float* Rf = reinterpret_cast<float*>(smem + 14592);   // R[16][33] floats
  u16* Os = reinterpret_cast<u16*>(smem);               // epilogue: [12][16][72] u16

  const int p0 = pt * 16;

  // Q fragments: 3 heads x 2 k-chunks, p-rows = l15
  bf8 qf[3][2];
  #pragma unroll
  for (int hh = 0; hh < 3; ++hh) {
    int h = w * 3 + hh;
    const u16* Qp = Q + ((size_t)(b * H_ + h) * P_ + p0 + l15) * HD_;
    qf[hh][0] = *reinterpret_cast<const bf8*>(Qp + quad * 8);
    qf[hh][1] = *reinterpret_cast<const bf8*>(Qp + 32 + quad * 8);
  }

  f4 oacc[3][4];  // per head: O^T d(4x16) x p(16)
  #pragma unroll
  for (int i = 0; i < 3; ++i)
    #pragma unroll
    for (int j = 0; j < 4; ++j) oacc[i][j] = f4{0.f, 0.f, 0.f, 0.f};

  for (int qt = 0; qt < 32; ++qt) {
    // --- S^T + exp -> E for this wave's 3 heads ---
    #pragma unroll
    for (int hh = 0; hh < 3; ++hh) {
      int h = w * 3 + hh;
      const u16* Kp = Km + ((size_t)(b * H_ + h) * P_ + qs * 1024 + qt * 32) * HD_;
      bf8 kf[2][2];
      #pragma unroll
      for (int mt = 0; mt < 2; ++mt) {
        kf[mt][0] = *reinterpret_cast<const bf8*>(Kp + (size_t)(mt * 16 + l15) * HD_ + quad * 8);
        kf[mt][1] = *reinterpret_cast<const bf8*>(Kp + (size_t)(mt * 16 + l15) * HD_ + 32 + quad * 8);
      }
      #pragma unroll
      for (int mt = 0; mt < 2; ++mt) {
        f4 s = {0.f, 0.f, 0.f, 0.f};
        s = mfma16(kf[mt][0], qf[hh][0], s);
        s = mfma16(kf[mt][1], qf[hh][1], s);
        f4 e;
        #pragma unroll
        for (int r = 0; r < 4; ++r) e[r] = __builtin_amdgcn_exp2f(s[r] * EXPC_);
        uint2 pk = pack4(e);
        int idx = (h * 16 + l15) * 19 + mt * 8 + quad * 2;  // q = mt*16+quad*4
        E32[idx] = pk.x;
        E32[idx + 1] = pk.y;
      }
    }
    __syncthreads();
    // --- R[p][q] = 1/sum_h E (128 threads, one f4 chunk each) ---
    if (threadIdx.x < 128) {
      int p = threadIdx.x >> 3, qc = (threadIdx.x & 7) * 4;
      f4 sum = {0.f, 0.f, 0.f, 0.f};
      #pragma unroll
      for (int h = 0; h < 12; ++h) {
        int idx = (h * 16 + p) * 19 + (qc >> 1);
        sum += unp2(E32[idx], E32[idx + 1]);
      }
      #pragma unroll
      for (int c = 0; c < 4; ++c)
        Rf[p * 33 + qc + c] = __builtin_amdgcn_rcpf(sum[c]);
    }
    __syncthreads();
    // --- AV: O^T += V^T-frag @ (E*R)-frag for own heads ---
    f4 r0, r1;
    #pragma unroll
    for (int c = 0; c < 4; ++c) {
      r0[c] = Rf[l15 * 33 + quad * 8 + c];
      r1[c] = Rf[l15 * 33 + quad * 8 + 4 + c];
    }
    #pragma unroll
    for (int hh = 0; hh < 3; ++hh) {
      int h = w * 3 + hh;
      int idx = (h * 16 + l15) * 19 + quad * 4;
      bf8 af = mkbf8(unp2(E32[idx], E32[idx + 1]) * r0,
                     unp2(E32[idx + 2], E32[idx + 3]) * r1);
      const u16* Vp = Vt + (size_t)(b * H_ + h) * HD_ * P_ + qs * 1024 + qt * 32;
      #pragma unroll
      for (int dt = 0; dt < 4; ++dt) {
        bf8 vf = *reinterpret_cast<const bf8*>(Vp + (size_t)(dt * 16 + l15) * P_ + quad * 8);
        oacc[hh][dt] = mfma16(vf, af, oacc[hh][dt]);
      }
    }
    // no trailing barrier: E regions single-writer/reader per wave; R guarded by the 2 barriers
  }
  __syncthreads();  // all AV done before Os aliases E
  // --- stage O^T (bf16) -> Os[12][16][72], then coalesced global write ---
  #pragma unroll
  for (int hh = 0; hh < 3; ++hh) {
    int h = w * 3 + hh;
    #pragma unroll
    for (int dt = 0; dt < 4; ++dt)
      *reinterpret_cast<uint2*>(&Os[(h * 16 + l15) * 72 + dt * 16 + quad * 4]) = pack4(oacc[hh][dt]);
  }
  __syncthreads();
  u16* Op = qs ? O1 : O0;
  #pragma unroll
  for (int j = 0; j < 12; ++j) {
    int c = threadIdx.x + j * 256;   // 0..3071
    int p = c / 192, m = c % 192;
    int h = m >> 4, d4 = (m & 15) * 4;
    uint2 val = *reinterpret_cast<const uint2*>(&Os[(h * 16 + p) * 72 + d4]);
    size_t go = ((size_t)(b * P_) + p0 + p) * D_ + h * 64 + d4;
    *reinterpret_cast<uint2*>(Op + go) = val;
  }
}

extern "C" void kernel_launch(void* const* d_in, const int* in_sizes, int n_in,
                              void* d_out, int out_size, void* d_ws, size_t ws_size,
                              hipStream_t stream) {
  const float* x = (const float*)d_in[0];
  const float* ln1w = (const float*)d_in[1];
  const float* ln1b = (const float*)d_in[2];
  const float* wqkv = (const float*)d_in[3];
  const float* bqkv = (const float*)d_in[4];
  const float* ln2w = (const float*)d_in[5];
  const float* ln2b = (const float*)d_in[6];
  const float* wfc1 = (const float*)d_in[7];
  const float* bfc1 = (const float*)d_in[8];
  const float* wfc2 = (const float*)d_in[9];
  const float* bfc2 = (const float*)d_in[10];
  float* out = (float*)d_out;

  char* ws = (char*)d_ws;
  size_t off = 0;
  auto alloc = [&](size_t bytes) -> void* {
    void* p = ws + off;
    off += (bytes + 255) & ~(size_t)255;
    return p;
  };
  u16* hln = (u16*)alloc((size_t)8192 * 768 * 2);
  u16* wqkvT = (u16*)alloc((size_t)2304 * 768 * 2);
  u16* wfc1T = (u16*)alloc((size_t)3072 * 768 * 2);
  u16* wfc2T = (u16*)alloc((size_t)768 * 3072 * 2);
  u16* Qb = (u16*)alloc((size_t)B_ * H_ * P_ * HD_ * 2);
  u16* Kb = (u16*)alloc((size_t)B_ * H_ * P_ * HD_ * 2);
  u16* Vtb = (u16*)alloc((size_t)B_ * H_ * HD_ * P_ * 2);
  float* x2 = (float*)alloc((size_t)8192 * 768 * 4);
  u16* O0 = (u16*)alloc((size_t)8192 * 768 * 2);
  u16* O1 = (u16*)alloc((size_t)8192 * 768 * 2);
  u16* gbuf = (u16*)alloc((size_t)8192 * 3072 * 2);

  tcast_k<<<dim3(72, 24), 256, 0, stream>>>(wqkv, wqkvT, 768, 2304);
  tcast_k<<<dim3(96, 24), 256, 0, stream>>>(wfc1, wfc1T, 768, 3072);
  tcast_k<<<dim3(24, 96), 256, 0, stream>>>(wfc2, wfc2T, 3072, 768);
  ln_k<<<8192, 256, 0, stream>>>(x, ln1w, ln1b, hln);
  gemm_qkv_k<<<dim3(18, 64), 256, 0, stream>>>(hln, wqkvT, bqkv, Qb, Kb, Vtb);
  attn_fused_k<<<1024, 256, 0, stream>>>(Qb, Kb, Vtb, O0, O1);
  ln2add_k<<<8192, 256, 0, stream>>>(x, O0, O1, ln2w, ln2b, x2, hln);
  gemm_fc1_k<<<dim3(24, 64), 256, 0, stream>>>(hln, wfc1T, bfc1, gbuf);
  gemm_fc2_k<<<dim3(12, 64), 256, 0, stream>>>(gbuf, wfc2T, bfc2, x2, out);
}